// Round 1
// baseline (616.931 us; speedup 1.0000x reference)
//
#include <hip/hip_runtime.h>
#include <stdint.h>

// Problem constants
#define IN_F   4096
#define OUT_F  11008
#define QCOLS  (OUT_F / 8)   // 1376
#define NGRP   32
#define M_TOT  4096

typedef __attribute__((ext_vector_type(8))) short short8;
typedef __attribute__((ext_vector_type(4))) float floatx4;

// fp32 -> bf16 round-to-nearest-even
__device__ __forceinline__ short f2bf(float f) {
    union { float f; uint32_t u; } v; v.f = f;
    uint32_t u = v.u;
    u += 0x7FFFu + ((u >> 16) & 1u);
    return (short)(u >> 16);
}

// ---------------------------------------------------------------------------
// Kernel 1: dequant qweight (4-bit, group=128) -> bf16 W^T[n][k] row-major.
// Block = 32-n x 512-k tile. qw tile staged TRANSPOSED in LDS.
// Writes: 8 consecutive lanes cover 128 B of ONE row -> 8x128B dense
// transactions per store instruction (the old kernel scattered 64x16B).
// ---------------------------------------------------------------------------
__global__ __launch_bounds__(256)
void dequant_kernel(const int* __restrict__ qw, const int* __restrict__ qz,
                    const float* __restrict__ scl, short* __restrict__ wt)
{
    __shared__ int qt[4][520];   // transposed [c][k], padded row (2-way max)

    const int tid = threadIdx.x;
    const int nb  = blockIdx.x;          // 0..343  (n-tile of 32)
    const int kb  = blockIdx.y;          // 0..7    (k-tile of 512)
    const int n0  = nb * 32;
    const int c0  = nb * 4;
    const int k0  = kb * 512;

    // ---- stage qw tile: 512k x 4c ints, coalesced-ish (16B chunks)
    #pragma unroll
    for (int i = 0; i < 8; ++i) {
        const int f = tid + i * 256;                 // 0..2047
        qt[f & 3][f >> 2] = qw[(size_t)(k0 + (f >> 2)) * QCOLS + c0 + (f & 3)];
    }
    __syncthreads();

    // thread -> (row n, 8-k slice); lanes 0..7 share n, cover 64 consecutive k
    const int n  = n0 + (tid >> 3);
    const int cl = tid >> 6;                         // int-col within tile (0..3)
    const int sh = (n & 7) << 2;                     // nibble shift
    const int ks = (tid & 7) << 3;                   // k base within 64

    short* dst = wt + (size_t)n * IN_F + k0 + ks;

    #pragma unroll
    for (int ip = 0; ip < 4; ++ip) {                 // 4 quant groups in tile
        const int g = kb * 4 + ip;
        const uint32_t z  = (uint32_t)qz[(size_t)g * QCOLS + c0 + cl];
        const float    sc = scl[(size_t)g * OUT_F + n];
        const float    zo = -(float)((z >> sh) & 15u) * sc;
        #pragma unroll
        for (int ih = 0; ih < 2; ++ih) {
            const int i = ip * 2 + ih;               // 64-k sub-block
            const int4 q0 = *(const int4*)&qt[cl][i * 64 + ks];
            const int4 q1 = *(const int4*)&qt[cl][i * 64 + ks + 4];
            short8 o;
            o[0] = f2bf(fmaf((float)(((uint32_t)q0.x >> sh) & 15u), sc, zo));
            o[1] = f2bf(fmaf((float)(((uint32_t)q0.y >> sh) & 15u), sc, zo));
            o[2] = f2bf(fmaf((float)(((uint32_t)q0.z >> sh) & 15u), sc, zo));
            o[3] = f2bf(fmaf((float)(((uint32_t)q0.w >> sh) & 15u), sc, zo));
            o[4] = f2bf(fmaf((float)(((uint32_t)q1.x >> sh) & 15u), sc, zo));
            o[5] = f2bf(fmaf((float)(((uint32_t)q1.y >> sh) & 15u), sc, zo));
            o[6] = f2bf(fmaf((float)(((uint32_t)q1.z >> sh) & 15u), sc, zo));
            o[7] = f2bf(fmaf((float)(((uint32_t)q1.w >> sh) & 15u), sc, zo));
            *(short8*)(dst + i * 64) = o;
        }
    }
}

// ---------------------------------------------------------------------------
// Kernel 2: cast A fp32 -> bf16 (row-major [m][k]) in workspace
// ---------------------------------------------------------------------------
__global__ __launch_bounds__(256)
void cast_kernel(const float* __restrict__ A, short* __restrict__ Ab)
{
    const size_t i = ((size_t)blockIdx.x * 256 + threadIdx.x) * 8;
    const float4 a0 = *(const float4*)(A + i);
    const float4 a1 = *(const float4*)(A + i + 4);
    short8 o;
    o[0] = f2bf(a0.x); o[1] = f2bf(a0.y); o[2] = f2bf(a0.z); o[3] = f2bf(a0.w);
    o[4] = f2bf(a1.x); o[5] = f2bf(a1.y); o[6] = f2bf(a1.z); o[7] = f2bf(a1.w);
    *(short8*)(Ab + i) = o;
}

// ---------------------------------------------------------------------------
// Kernel 3: bf16 GEMM, 256x256 tile, 8-phase counted-vmcnt schedule (m201
// template). 8 waves (2M x 4N), BK=64, 128 KiB LDS double-buffer, XOR-swizzled
// (linear LDS dest + pre-swizzled global source + swizzled ds_read).
// Per phase: {ds_read subtile | stage 1 half-tile} -> barrier -> 16 MFMA
// (setprio) -> lgkmcnt(0) -> barrier.  vmcnt(4) once per K-tile, never 0.
// Schedule: A(j+1) staged at P1/P2 into buf^1 (slots dead since j-1);
// B(j+2) staged at P3/P4 into cur buf AFTER its B reads (P1/P2).
// ---------------------------------------------------------------------------
#define GLL(src, dst) __builtin_amdgcn_global_load_lds(                        \
    (const __attribute__((address_space(1))) void*)(src),                      \
    (__attribute__((address_space(3))) void*)(dst), 16, 0, 0)

#define BAR()  do { asm volatile("" ::: "memory");                             \
                    __builtin_amdgcn_s_barrier();                              \
                    asm volatile("" ::: "memory"); } while (0)

__global__ __launch_bounds__(512, 2)
void gemm256_kernel(const short* __restrict__ Ab, const short* __restrict__ Bt,
                    float* __restrict__ out)
{
    __shared__ short As[2][2][8192];   // [dbuf][half][128*64]  64 KiB
    __shared__ short Bs[2][2][8192];   // 64 KiB

    const int tid  = threadIdx.x;      // 0..511
    const int lane = tid & 63;
    const int w    = tid >> 6;         // 0..7
    const int wm   = w >> 2;           // 0..1  (A half)
    const int wn   = w & 3;            // 0..3  (64-col chunk)
    const int m0   = blockIdx.x * 256; // m-fast dispatch
    const int n0   = blockIdx.y * 256;

    // ---- staging: flat = l*512 + tid; row = flat>>3 (l adds 64), seg = flat&7
    // pre-swizzled global source column (seg ^ row&7); LDS dest linear.
    const int r0 = tid >> 3;
    const int sg = (((tid & 7) ^ (r0 & 7)) << 3);

    const short* aS[2][2];   // [half][l]
    const short* bS[2][2];
    aS[0][0] = Ab + (size_t)(m0 +       r0) * IN_F + sg;
    aS[0][1] = Ab + (size_t)(m0 +  64 + r0) * IN_F + sg;
    aS[1][0] = Ab + (size_t)(m0 + 128 + r0) * IN_F + sg;
    aS[1][1] = Ab + (size_t)(m0 + 192 + r0) * IN_F + sg;
    bS[0][0] = Bt + (size_t)(n0 +       r0) * IN_F + sg;
    bS[0][1] = Bt + (size_t)(n0 +  64 + r0) * IN_F + sg;
    bS[1][0] = Bt + (size_t)(n0 + 128 + r0) * IN_F + sg;
    bS[1][1] = Bt + (size_t)(n0 + 192 + r0) * IN_F + sg;

    const int ld0 = (tid - lane) << 3;       // wave-uniform LDS base (shorts)
    const int ld1 = 4096 + ld0;              // l=1 half of the slot

    // ---- MFMA fragment roles
    const int lrow = lane & 15;
    const int quad = lane >> 4;
    const int sw   = ((quad ^ (lrow & 7)) << 3);

    int ao[8], bo[4];
    #pragma unroll
    for (int mt = 0; mt < 8; ++mt) ao[mt] = ((mt * 16 + lrow) << 6) + sw;
    #pragma unroll
    for (int nt = 0; nt < 4; ++nt)
        bo[nt] = ((((wn & 1) << 6) + nt * 16 + lrow) << 6) + sw;

    const short* Ard[2] = { &As[0][wm][0],      &As[1][wm][0] };
    const short* Brd[2] = { &Bs[0][wn >> 1][0], &Bs[1][wn >> 1][0] };

    floatx4 acc[8][4];
    #pragma unroll
    for (int i = 0; i < 8; ++i)
        #pragma unroll
        for (int j = 0; j < 4; ++j)
            acc[i][j] = (floatx4)0.f;

    // ---- prologue: K0 (B-lo,B-hi,A-lo,A-hi) + B(1) halves; vmcnt(4) -> K0 in
    GLL(bS[0][0], &Bs[0][0][ld0]); GLL(bS[0][1], &Bs[0][0][ld1]);
    GLL(bS[1][0], &Bs[0][1][ld0]); GLL(bS[1][1], &Bs[0][1][ld1]);
    GLL(aS[0][0], &As[0][0][ld0]); GLL(aS[0][1], &As[0][0][ld1]);
    GLL(aS[1][0], &As[0][1][ld0]); GLL(aS[1][1], &As[0][1][ld1]);
    GLL(bS[0][0] + 64, &Bs[1][0][ld0]); GLL(bS[0][1] + 64, &Bs[1][0][ld1]);
    GLL(bS[1][0] + 64, &Bs[1][1][ld0]); GLL(bS[1][1] + 64, &Bs[1][1][ld1]);
    asm volatile("s_waitcnt vmcnt(4)" ::: "memory");
    BAR();

    short8 af[4][2], b01[2][2], b23[2][2];

    for (int jj = 0; jj < 32; ++jj) {
        #pragma unroll
        for (int h = 0; h < 2; ++h) {
            const int j  = jj * 2 + h;
            const int kA = ((j + 1 < 64) ? j + 1 : 63) << 6;   // shorts
            const int kB = ((j + 2 < 64) ? j + 2 : 63) << 6;
            const short* Ac = Ard[h];
            const short* Bc = Brd[h];

            // ================ P1: A0-3 + B0-1 reads; stage A-lo(j+1)
            #pragma unroll
            for (int mt = 0; mt < 4; ++mt) {
                af[mt][0] = *(const short8*)(Ac + ao[mt]);
                af[mt][1] = *(const short8*)(Ac + (ao[mt] ^ 32));
            }
            #pragma unroll
            for (int nt = 0; nt < 2; ++nt) {
                b01[nt][0] = *(const short8*)(Bc + bo[nt]);
                b01[nt][1] = *(const short8*)(Bc + (bo[nt] ^ 32));
            }
            GLL(aS[0][0] + kA, &As[h ^ 1][0][ld0]);
            GLL(aS[0][1] + kA, &As[h ^ 1][0][ld1]);
            BAR();
            __builtin_amdgcn_s_setprio(1);
            #pragma unroll
            for (int kk = 0; kk < 2; ++kk)
                #pragma unroll
                for (int mt = 0; mt < 4; ++mt)
                    #pragma unroll
                    for (int nt = 0; nt < 2; ++nt)
                        acc[mt][nt] = __builtin_amdgcn_mfma_f32_16x16x32_bf16(
                            af[mt][kk], b01[nt][kk], acc[mt][nt], 0, 0, 0);
            __builtin_amdgcn_s_setprio(0);
            asm volatile("s_waitcnt lgkmcnt(0)" ::: "memory");
            BAR();

            // ================ P2: B2-3 reads; stage A-hi(j+1)
            #pragma unroll
            for (int nt = 0; nt < 2; ++nt) {
                b23[nt][0] = *(const short8*)(Bc + bo[nt + 2]);
                b23[nt][1] = *(const short8*)(Bc + (bo[nt + 2] ^ 32));
            }
            GLL(aS[1][0] + kA, &As[h ^ 1][1][ld0]);
            GLL(aS[1][1] + kA, &As[h ^ 1][1][ld1]);
            BAR();
            __builtin_amdgcn_s_setprio(1);
            #pragma unroll
            for (int kk = 0; kk < 2; ++kk)
                #pragma unroll
                for (int mt = 0; mt < 4; ++mt)
                    #pragma unroll
                    for (int nt = 0; nt < 2; ++nt)
                        acc[mt][nt + 2] = __builtin_amdgcn_mfma_f32_16x16x32_bf16(
                            af[mt][kk], b23[nt][kk], acc[mt][nt + 2], 0, 0, 0);
            __builtin_amdgcn_s_setprio(0);
            asm volatile("s_waitcnt lgkmcnt(0)" ::: "memory");
            BAR();

            // ================ P3: A4-7 reads; stage B-lo(j+2) (cur buf, B dead)
            #pragma unroll
            for (int mt = 0; mt < 4; ++mt) {
                af[mt][0] = *(const short8*)(Ac + ao[mt + 4]);
                af[mt][1] = *(const short8*)(Ac + (ao[mt + 4] ^ 32));
            }
            GLL(bS[0][0] + kB, &Bs[h][0][ld0]);
            GLL(bS[0][1] + kB, &Bs[h][0][ld1]);
            BAR();
            __builtin_amdgcn_s_setprio(1);
            #pragma unroll
            for (int kk = 0; kk < 2; ++kk)
                #pragma unroll
                for (int mt = 0; mt < 4; ++mt)
                    #pragma unroll
                    for (int nt = 0; nt < 2; ++nt)
                        acc[mt + 4][nt + 2] = __builtin_amdgcn_mfma_f32_16x16x32_bf16(
                            af[mt][kk], b23[nt][kk], acc[mt + 4][nt + 2], 0, 0, 0);
            __builtin_amdgcn_s_setprio(0);
            asm volatile("s_waitcnt lgkmcnt(0)" ::: "memory");
            BAR();

            // ================ P4: no reads; stage B-hi(j+2); vmcnt(4)
            GLL(bS[1][0] + kB, &Bs[h][1][ld0]);
            GLL(bS[1][1] + kB, &Bs[h][1][ld1]);
            BAR();
            __builtin_amdgcn_s_setprio(1);
            #pragma unroll
            for (int kk = 0; kk < 2; ++kk)
                #pragma unroll
                for (int mt = 0; mt < 4; ++mt)
                    #pragma unroll
                    for (int nt = 0; nt < 2; ++nt)
                        acc[mt + 4][nt] = __builtin_amdgcn_mfma_f32_16x16x32_bf16(
                            af[mt][kk], b01[nt][kk], acc[mt + 4][nt], 0, 0, 0);
            __builtin_amdgcn_s_setprio(0);
            // retire A(j+1)+B(j+1): next K-tile fully staged; keep B(j+2) in flight
            asm volatile("s_waitcnt vmcnt(4)" ::: "memory");
            BAR();
        }
    }

    // ---- epilogue: C/D layout col = lane&15, row = quad*4 + reg
    #pragma unroll
    for (int mt = 0; mt < 8; ++mt) {
        #pragma unroll
        for (int nt = 0; nt < 4; ++nt) {
            const int col = n0 + (wn << 6) + nt * 16 + lrow;
            float* op = out + (size_t)(m0 + (wm << 7) + mt * 16 + (quad << 2)) * OUT_F + col;
            #pragma unroll
            for (int r = 0; r < 4; ++r)
                op[(size_t)r * OUT_F] = acc[mt][nt][r];
        }
    }
}

// ---------------------------------------------------------------------------
// Fallback: round-1 fused kernel (used only if workspace is too small)
// ---------------------------------------------------------------------------
#define BM 128
#define BN 128
#define LDA 40
#define LDB 40

__global__ __launch_bounds__(256, 2)
void wql_kernel(const float* __restrict__ A,
                const int*   __restrict__ qw,
                const int*   __restrict__ qz,
                const float* __restrict__ scl,
                float*       __restrict__ out)
{
    __shared__ short As[BM * LDA];
    __shared__ short Bs[BN * LDB];

    const int tid = threadIdx.x;
    const int m0  = blockIdx.y * BM;
    const int n0  = blockIdx.x * BN;

    const int a_row  = tid >> 1;
    const int a_kseg = (tid & 1) << 4;
    const float* a_base = A + (size_t)(m0 + a_row) * IN_F + a_kseg;
    short* a_wr = &As[a_row * LDA + a_kseg];

    const int b_n     = tid & 127;
    const int b_khalf = (tid >> 7) << 4;
    const int c_glob  = (n0 >> 3) + (b_n >> 3);
    const int shift   = (b_n & 7) << 2;
    short* b_wr = &Bs[b_n * LDB + b_khalf];

    const int lane = tid & 63;
    const int wm   = ((tid >> 7) & 1) << 6;
    const int wn   = ((tid >> 6) & 1) << 6;
    const int lrow = lane & 15;
    const int quad = lane >> 4;

    const short* a_rd = &As[(wm + lrow) * LDA + quad * 8];
    const short* b_rd = &Bs[(wn + lrow) * LDB + quad * 8];

    floatx4 acc[4][4];
    #pragma unroll
    for (int i = 0; i < 4; ++i)
        #pragma unroll
        for (int j = 0; j < 4; ++j)
            acc[i][j] = (floatx4)0.f;

    for (int g = 0; g < NGRP; ++g) {
        const uint32_t z  = (uint32_t)qz[g * QCOLS + c_glob];
        const float    sc = scl[g * OUT_F + n0 + b_n];
        const float    zo = -(float)((z >> shift) & 15u) * sc;

        #pragma unroll 1
        for (int t4 = 0; t4 < 4; ++t4) {
            const int k0 = (g << 7) + (t4 << 5);
            const float4* ap = (const float4*)(a_base + k0);
            float4 av0 = ap[0], av1 = ap[1], av2 = ap[2], av3 = ap[3];

            const int* qp = qw + (size_t)(k0 + b_khalf) * QCOLS + c_glob;
            uint32_t qv[16];
            #pragma unroll
            for (int kk = 0; kk < 16; ++kk) qv[kk] = (uint32_t)qp[kk * QCOLS];

            __syncthreads();

            short8 aw0, aw1;
            aw0[0]=f2bf(av0.x); aw0[1]=f2bf(av0.y); aw0[2]=f2bf(av0.z); aw0[3]=f2bf(av0.w);
            aw0[4]=f2bf(av1.x); aw0[5]=f2bf(av1.y); aw0[6]=f2bf(av1.z); aw0[7]=f2bf(av1.w);
            aw1[0]=f2bf(av2.x); aw1[1]=f2bf(av2.y); aw1[2]=f2bf(av2.z); aw1[3]=f2bf(av2.w);
            aw1[4]=f2bf(av3.x); aw1[5]=f2bf(av3.y); aw1[6]=f2bf(av3.z); aw1[7]=f2bf(av3.w);
            *(short8*)a_wr       = aw0;
            *(short8*)(a_wr + 8) = aw1;

            short8 bw0, bw1;
            #pragma unroll
            for (int kk = 0; kk < 8; ++kk)
                bw0[kk] = f2bf(fmaf((float)((qv[kk] >> shift) & 15u), sc, zo));
            #pragma unroll
            for (int kk = 0; kk < 8; ++kk)
                bw1[kk] = f2bf(fmaf((float)((qv[8 + kk] >> shift) & 15u), sc, zo));
            *(short8*)b_wr       = bw0;
            *(short8*)(b_wr + 8) = bw1;

            __syncthreads();

            short8 af[4], bf[4];
            #pragma unroll
            for (int mt = 0; mt < 4; ++mt)
                af[mt] = *(const short8*)(a_rd + mt * 16 * LDA);
            #pragma unroll
            for (int nt = 0; nt < 4; ++nt)
                bf[nt] = *(const short8*)(b_rd + nt * 16 * LDB);

            #pragma unroll
            for (int mt = 0; mt < 4; ++mt)
                #pragma unroll
                for (int nt = 0; nt < 4; ++nt)
                    acc[mt][nt] = __builtin_amdgcn_mfma_f32_16x16x32_bf16(
                        af[mt], bf[nt], acc[mt][nt], 0, 0, 0);
        }
    }

    #pragma unroll
    for (int mt = 0; mt < 4; ++mt) {
        #pragma unroll
        for (int nt = 0; nt < 4; ++nt) {
            const int col = n0 + wn + nt * 16 + lrow;
            float* op = out + (size_t)(m0 + wm + mt * 16 + quad * 4) * OUT_F + col;
            #pragma unroll
            for (int r = 0; r < 4; ++r)
                op[(size_t)r * OUT_F] = acc[mt][nt][r];
        }
    }
}

extern "C" void kernel_launch(void* const* d_in, const int* in_sizes, int n_in,
                              void* d_out, int out_size, void* d_ws, size_t ws_size,
                              hipStream_t stream) {
    const float* input   = (const float*)d_in[0];
    const int*   qweight = (const int*)d_in[1];
    const int*   qzeros  = (const int*)d_in[2];
    const float* scales  = (const float*)d_in[3];
    float*       out     = (float*)d_out;

    const size_t WT_BYTES = (size_t)OUT_F * IN_F * 2;   // 90,177,536
    const size_t AB_BYTES = (size_t)M_TOT * IN_F * 2;   // 33,554,432

    if (ws_size >= WT_BYTES + AB_BYTES) {
        short* wt = (short*)d_ws;
        short* ab = (short*)((char*)d_ws + WT_BYTES);

        dim3 dq_grid(OUT_F / 32, IN_F / 512);   // (344, 8)
        dequant_kernel<<<dq_grid, 256, 0, stream>>>(qweight, qzeros, scales, wt);
        cast_kernel<<<(size_t)M_TOT * IN_F / 8 / 256, 256, 0, stream>>>(input, ab);
        dim3 grid(M_TOT / 256, OUT_F / 256);    // (16, 43), m-fast
        gemm256_kernel<<<grid, 512, 0, stream>>>(ab, wt, out);
    } else {
        dim3 grid(OUT_F / BN, M_TOT / BM);
        wql_kernel<<<grid, 256, 0, stream>>>(input, qweight, qzeros, scales, out);
    }
}